// Round 3
// baseline (406.349 us; speedup 1.0000x reference)
//
#include <hip/hip_runtime.h>

// Problem constants: B=4, C=32, D=H=W=64, N(fuzzy)=4
constexpr int Cc = 32;
constexpr int SP = 64 * 64 * 64;   // 262144 spatial per batch
constexpr int TS = 4 * SP;         // 1048576 total spatial

// Padded fuzz layout: [B][66][66][68] (z,y,w each +1 halo; w +2 extra for pitch)
constexpr int PW  = 68;
constexpr int PZR = 66 * PW;       // 4488 floats per (z, all-y) slice
constexpr int PSP = 66 * PZR;      // 296208 floats per batch
constexpr int PTOT = 4 * PSP;      // 1184832 floats

// Workspace layout (floats): [0, PTOT) padded RAW fuzz; acc = ws+PTOT:
//   acc[0..2): bn1 sum,sumsq   acc[2..4): bn1 a,sh
//   acc[4..36): bn2 scale      acc[36..68): bn2 shift
//   acc[68..68+4096): bn2 partial sums, idx = 68 + (st*32+c)*64 + slot
//   acc[4164..4164+864): W27 table, idx = c*27 + zc*9 + yc*3 + xc
constexpr int WOFF  = 68 + 64 * 64;      // 4164
constexpr int ACC_N = WOFF + 864;        // 5028

// ---------------- Kernel 1: conv1 (32->1, 3x3x3 SAME) + fuzzy + bn1 stats
// 2z x 4w register tile, branchless clamped loads, DEPTH-2 prefetch
// (4 rotating 12x float4 buffers; loads issued 2 channel-computes early).
__global__ __launch_bounds__(256) void k_conv1_fuzzy(
    const float* __restrict__ x, const float* __restrict__ w1,
    const float* __restrict__ b1, const float* __restrict__ mu,
    const float* __restrict__ sg, float* __restrict__ fuzz,
    float* __restrict__ acc)
{
    const int tid = threadIdx.x;
    const int t = blockIdx.x * 256 + tid;        // 131072 threads
    const int wq = t & 15;        const int w0 = wq << 2;
    const int zp = (t >> 4) & 31; const int z0 = zp << 1;
    const int y  = (t >> 9) & 63;
    const int b  = t >> 15;
    const int lane = tid & 63;

    float S1 = 0.f, S2 = 0.f, S3 = 0.f;
#pragma unroll
    for (int n = 0; n < 4; n++) {
        float m = mu[n], s = sg[n];
        float iv = 1.0f / (s * s);
        S1 += iv; S2 += m * iv; S3 += m * m * iv;
    }

    const float b1v = b1[0];
    float a00 = b1v, a01 = b1v, a02 = b1v, a03 = b1v;
    float a10 = b1v, a11 = b1v, a12 = b1v, a13 = b1v;

    const float* xb = x + (size_t)b * Cc * SP;

    // channel-invariant row predicates + CLAMPED offsets (always-valid addrs)
    bool pv[12]; int ofs[12];
#pragma unroll
    for (int rz = 0; rz < 4; rz++) {
        const int zz = z0 - 1 + rz;
        const int zzc = min(max(zz, 0), 63);
        const bool okz = (unsigned)zz < 64u;
#pragma unroll
        for (int dy = 0; dy < 3; dy++) {
            const int yy = y - 1 + dy;
            const int yyc = min(max(yy, 0), 63);
            pv[rz * 3 + dy]  = okz && ((unsigned)yy < 64u);
            ofs[rz * 3 + dy] = (zzc << 12) + (yyc << 6) + w0;
        }
    }

    auto LOADCH = [&](int c, float4 (&M)[12]) {
        const float* xc = xb + (size_t)c * SP;
#pragma unroll
        for (int i = 0; i < 12; i++)
            M[i] = *(const float4*)(xc + ofs[i]);   // unconditional, clustered
    };

    auto COMPUTECH = [&](int c, float4 (&M)[12]) {
        // zero invalid rows (vmcnt wait lands here; loads were issued two
        // channel-computes earlier)
#pragma unroll
        for (int i = 0; i < 12; i++) {
            M[i].x = pv[i] ? M[i].x : 0.f;
            M[i].y = pv[i] ? M[i].y : 0.f;
            M[i].z = pv[i] ? M[i].z : 0.f;
            M[i].w = pv[i] ? M[i].w : 0.f;
        }
        const float* wc = w1 + c * 27;           // uniform -> s_load
        float Wv[27];
#pragma unroll
        for (int k = 0; k < 27; k++) Wv[k] = wc[k];
#pragma unroll
        for (int rz = 0; rz < 4; rz++) {
#pragma unroll
            for (int dy = 0; dy < 3; dy++) {
                const float4 m = M[rz * 3 + dy];
                const float lv = __shfl(m.w, (lane + 63) & 63, 64);
                const float rv = __shfl(m.x, (lane + 1) & 63, 64);
                const float v0 = (wq > 0)  ? lv : 0.f;
                const float v5 = (wq < 15) ? rv : 0.f;
                const float v1 = m.x, v2 = m.y, v3 = m.z, v4 = m.w;
                if (rz < 3) {
                    const float W0 = Wv[(rz*3+dy)*3], W1 = Wv[(rz*3+dy)*3+1], W2 = Wv[(rz*3+dy)*3+2];
                    a00 = fmaf(v0, W0, fmaf(v1, W1, fmaf(v2, W2, a00)));
                    a01 = fmaf(v1, W0, fmaf(v2, W1, fmaf(v3, W2, a01)));
                    a02 = fmaf(v2, W0, fmaf(v3, W1, fmaf(v4, W2, a02)));
                    a03 = fmaf(v3, W0, fmaf(v4, W1, fmaf(v5, W2, a03)));
                }
                if (rz >= 1) {
                    const float W0 = Wv[((rz-1)*3+dy)*3], W1 = Wv[((rz-1)*3+dy)*3+1], W2 = Wv[((rz-1)*3+dy)*3+2];
                    a10 = fmaf(v0, W0, fmaf(v1, W1, fmaf(v2, W2, a10)));
                    a11 = fmaf(v1, W0, fmaf(v2, W1, fmaf(v3, W2, a11)));
                    a12 = fmaf(v2, W0, fmaf(v3, W1, fmaf(v4, W2, a12)));
                    a13 = fmaf(v3, W0, fmaf(v4, W1, fmaf(v5, W2, a13)));
                }
            }
        }
    };

    float4 Ba[12], Bb[12], Bc[12], Bd[12];
    LOADCH(0, Ba);
    LOADCH(1, Bb);
    for (int c = 0; c < Cc; c += 4) {
        LOADCH(c + 2, Bc);
        COMPUTECH(c, Ba);
        LOADCH(c + 3, Bd);
        COMPUTECH(c + 1, Bb);
        if (c + 4 < Cc) LOADCH(c + 4, Ba);
        COMPUTECH(c + 2, Bc);
        if (c + 5 < Cc) LOADCH(c + 5, Bb);
        COMPUTECH(c + 3, Bd);
    }

    // fuzzy + store RAW fuzz into padded layout + bn1 stats
    float fsum = 0.f, fsq = 0.f;
#pragma unroll
    for (int oz = 0; oz < 2; oz++) {
        float xv[4] = { oz ? a10 : a00, oz ? a11 : a01,
                        oz ? a12 : a02, oz ? a13 : a03 };
        float* fp = fuzz + (size_t)b * PSP + (size_t)(z0 + oz + 1) * PZR
                  + (y + 1) * PW + (w0 + 1);
#pragma unroll
        for (int ow = 0; ow < 4; ow++) {
            float x1 = xv[ow];
            float tt = x1 * x1 * S1 - 2.0f * x1 * S2 + S3;
            float fz = __expf(-tt);
            fp[ow] = fz; fsum += fz; fsq += fz * fz;
        }
    }
#pragma unroll
    for (int m = 1; m < 64; m <<= 1) {
        fsum += __shfl_xor(fsum, m, 64);
        fsq  += __shfl_xor(fsq,  m, 64);
    }
    __shared__ float red[8];
    const int wid = tid >> 6;
    if ((tid & 63) == 0) { red[wid * 2] = fsum; red[wid * 2 + 1] = fsq; }
    __syncthreads();
    if (tid == 0) {
        atomicAdd(&acc[0], red[0] + red[2] + red[4] + red[6]);
        atomicAdd(&acc[1], red[1] + red[3] + red[5] + red[7]);
    }
}

// ---------------- Kernel 2: finalize bn1 -> (a, sh); build W27 boundary table.
// W27[c][zc][yc][xc] = sum of w2 taps valid for that boundary class
// (class 0: coord==0 -> d in {1,2}; class 2: coord==63 -> d in {0,1}; else all).
__global__ void k_fin1(const float* __restrict__ g, const float* __restrict__ be,
                       const float* __restrict__ w2, float* __restrict__ acc)
{
    const int tid = threadIdx.x;          // 864 threads
    if (tid == 0) {
        float mean = acc[0] * (1.0f / TS);
        float var  = acc[1] * (1.0f / TS) - mean * mean;
        float a = g[0] * rsqrtf(var + 1e-5f);
        acc[2] = a;
        acc[3] = be[0] - mean * a;
    }
    if (tid < 864) {
        const int c   = tid / 27;
        const int cls = tid - c * 27;
        const int zc  = cls / 9;
        const int r   = cls - zc * 9;
        const int yc  = r / 3;
        const int xc  = r - yc * 3;
        float s = 0.f;
#pragma unroll
        for (int dz = 0; dz < 3; dz++) {
            if ((zc == 0 && dz == 0) || (zc == 2 && dz == 2)) continue;
#pragma unroll
            for (int dy = 0; dy < 3; dy++) {
                if ((yc == 0 && dy == 0) || (yc == 2 && dy == 2)) continue;
#pragma unroll
                for (int dx = 0; dx < 3; dx++) {
                    if ((xc == 0 && dx == 0) || (xc == 2 && dx == 2)) continue;
                    s += w2[c * 27 + (dz * 3 + dy) * 3 + dx];
                }
            }
        }
        acc[WOFF + tid] = s;
    }
}

// ---------------- Kernel 3/5: conv2 on RAW padded fuzz with folded bn1 affine.
//   y = a * (sum w2 * fuzz_raw) + (sh * W27[class] + b2)
// STATS instantiation: butterfly-reduce y, y^2 -> slot atomics (no y write).
// WRITE instantiation: recompute y, apply bn2 affine, single 128 MiB store.
template <bool WRITE>
__global__ __launch_bounds__(256) void k_conv2(
    const float* __restrict__ fuzz, const float* __restrict__ w2,
    const float* __restrict__ b2, float* __restrict__ acc,
    float* __restrict__ out)
{
    const int tid = threadIdx.x;
    const int lane = tid & 63;
    const int wid = tid >> 6;              // channel group 0..3
    const int bi = blockIdx.x;             // 4096 spatial tiles
    const int w = lane;
    const int y = bi & 63;
    const int z0 = ((bi >> 6) & 15) << 2;
    const int b = bi >> 10;
    const float a = acc[2], sh = acc[3];
    const float* fb = fuzz + (size_t)b * PSP;

    float Fl[6][3], Fm[6][3], Fr[6][3];
#pragma unroll
    for (int rz = 0; rz < 6; rz++) {
#pragma unroll
        for (int dy = 0; dy < 3; dy++) {
            const float* rp = fb + (size_t)(z0 + rz) * PZR + (y + dy) * PW + w;
            Fl[rz][dy] = rp[0];
            Fm[rz][dy] = rp[1];
            Fr[rz][dy] = rp[2];
        }
    }

    // boundary classes: z0+1, z0+2 are always interior (z0 in 0..60 step 4)
    const int yc  = (y == 0) ? 0 : ((y == 63) ? 2 : 1);
    const int zc0 = (z0 == 0) ? 0 : 1;
    const int zc3 = (z0 + 3 == 63) ? 2 : 1;
    const bool lo = (lane == 0), hi = (lane == 63);

    float* ob = out + (size_t)b * Cc * SP + (z0 << 12) + (y << 6) + w;
    const int slot = bi & 63;
    const int c0 = wid * 8;

#pragma unroll
    for (int ci = 0; ci < 8; ci++) {
        const int c = c0 + ci;
        const float* wc = w2 + c * 27;     // uniform -> s_load
        float Wv[27];
#pragma unroll
        for (int k = 0; k < 27; k++) Wv[k] = wc[k];
        float o0 = 0.f, o1 = 0.f, o2 = 0.f, o3 = 0.f;
#pragma unroll
        for (int rz = 0; rz < 6; rz++) {
#pragma unroll
            for (int dy = 0; dy < 3; dy++) {
                const float l = Fl[rz][dy], m = Fm[rz][dy], r = Fr[rz][dy];
#pragma unroll
                for (int oz = 0; oz < 4; oz++) {
                    const int dz = rz - oz;
                    if (dz < 0 || dz > 2) continue;
                    const float W0 = Wv[(dz*3+dy)*3], W1 = Wv[(dz*3+dy)*3+1], W2 = Wv[(dz*3+dy)*3+2];
                    if      (oz == 0) o0 = fmaf(l, W0, fmaf(m, W1, fmaf(r, W2, o0)));
                    else if (oz == 1) o1 = fmaf(l, W0, fmaf(m, W1, fmaf(r, W2, o1)));
                    else if (oz == 2) o2 = fmaf(l, W0, fmaf(m, W1, fmaf(r, W2, o2)));
                    else              o3 = fmaf(l, W0, fmaf(m, W1, fmaf(r, W2, o3)));
                }
            }
        }
        // per-oz bn1-fold offsets: off = b2 + sh * W27[c][zc][yc][xc(lane)]
        const float bb = b2[c];
        const float* tb = acc + WOFF + c * 27 + yc * 3;   // + zc*9 + xc
        const float* t0 = tb + zc0 * 9;
        const float* t1 = tb + 9;                          // zc == 1
        const float* t3 = tb + zc3 * 9;
        const float w0s = lo ? t0[0] : (hi ? t0[2] : t0[1]);
        const float w1s = lo ? t1[0] : (hi ? t1[2] : t1[1]);
        const float w3s = lo ? t3[0] : (hi ? t3[2] : t3[1]);
        const float off0 = fmaf(sh, w0s, bb);
        const float off1 = fmaf(sh, w1s, bb);   // oz=1 and oz=2 share class
        const float off3 = fmaf(sh, w3s, bb);
        const float v0 = fmaf(o0, a, off0);
        const float v1 = fmaf(o1, a, off1);
        const float v2 = fmaf(o2, a, off1);
        const float v3 = fmaf(o3, a, off3);

        if (WRITE) {
            const float sc = acc[4 + c], s2 = acc[36 + c];
            ob[(size_t)c * SP]         = fmaf(v0, sc, s2);
            ob[(size_t)c * SP + 4096]  = fmaf(v1, sc, s2);
            ob[(size_t)c * SP + 8192]  = fmaf(v2, sc, s2);
            ob[(size_t)c * SP + 12288] = fmaf(v3, sc, s2);
        } else {
            float ps = (v0 + v1) + (v2 + v3);
            float pq = fmaf(v0, v0, fmaf(v1, v1, fmaf(v2, v2, v3 * v3)));
#pragma unroll
            for (int mm = 1; mm < 64; mm <<= 1) {
                ps += __shfl_xor(ps, mm, 64);
                pq += __shfl_xor(pq, mm, 64);
            }
            if (lane == 0) {
                atomicAdd(&acc[68 + c * 64 + slot], ps);
                atomicAdd(&acc[68 + (32 + c) * 64 + slot], pq);
            }
        }
    }
}

// ---------------- Kernel 4: finalize bn2 (parallel: 1024 threads, shfl-reduce)
__global__ void k_fin2(const float* __restrict__ g, const float* __restrict__ be,
                       float* __restrict__ acc)
{
    const int tid = threadIdx.x;          // 1024 threads
    const int c = tid >> 5, j = tid & 31;
    float s = acc[68 + c * 64 + j]        + acc[68 + c * 64 + 32 + j];
    float q = acc[68 + (32 + c) * 64 + j] + acc[68 + (32 + c) * 64 + 32 + j];
#pragma unroll
    for (int m = 1; m < 32; m <<= 1) {
        s += __shfl_xor(s, m, 32);
        q += __shfl_xor(q, m, 32);
    }
    if (j == 0) {
        float mean = s * (1.0f / TS);
        float var  = q * (1.0f / TS) - mean * mean;
        float sc = g[c] * rsqrtf(var + 1e-5f);
        acc[4 + c]  = sc;
        acc[36 + c] = be[c] - mean * sc;
    }
}

extern "C" void kernel_launch(void* const* d_in, const int* in_sizes, int n_in,
                              void* d_out, int out_size, void* d_ws, size_t ws_size,
                              hipStream_t stream)
{
    const float* x   = (const float*)d_in[0];
    const float* w1  = (const float*)d_in[1];
    const float* b1  = (const float*)d_in[2];
    const float* w2  = (const float*)d_in[3];
    const float* b2  = (const float*)d_in[4];
    const float* mu  = (const float*)d_in[5];
    const float* sg  = (const float*)d_in[6];
    const float* g1  = (const float*)d_in[7];
    const float* be1 = (const float*)d_in[8];
    const float* g2  = (const float*)d_in[9];
    const float* be2 = (const float*)d_in[10];

    float* out  = (float*)d_out;
    float* fuzz = (float*)d_ws;
    float* acc  = fuzz + PTOT;

    // zero padded fuzz (pad ring must be 0 each launch) + acc area in one shot
    hipMemsetAsync(fuzz, 0, (size_t)(PTOT + ACC_N) * sizeof(float), stream);
    k_conv1_fuzzy<<<512, 256, 0, stream>>>(x, w1, b1, mu, sg, fuzz, acc);
    k_fin1<<<1, 864, 0, stream>>>(g1, be1, w2, acc);
    k_conv2<false><<<4096, 256, 0, stream>>>(fuzz, w2, b2, acc, out);
    k_fin2<<<1, 1024, 0, stream>>>(g2, be2, acc);
    k_conv2<true><<<4096, 256, 0, stream>>>(fuzz, w2, b2, acc, out);
}

// Round 4
// 355.287 us; speedup vs baseline: 1.1437x; 1.1437x over previous
//
#include <hip/hip_runtime.h>

// Problem constants: B=4, C=32, D=H=W=64, N(fuzzy)=4
constexpr int Cc = 32;
constexpr int SP = 64 * 64 * 64;   // 262144 spatial per batch
constexpr int TS = 4 * SP;         // 1048576 total spatial

// Padded fuzz layout: [B][66][66][68] (z,y,w each +1 halo; w +2 extra for pitch)
constexpr int PW  = 68;
constexpr int PZR = 66 * PW;       // 4488 floats per (z, all-y) slice
constexpr int PSP = 66 * PZR;      // 296208 floats per batch
constexpr int PTOT = 4 * PSP;      // 1184832 floats

// Workspace layout (floats): [0, PTOT) padded RAW fuzz; acc = ws+PTOT:
//   acc[0..2): bn1 sum,sumsq   acc[2..4): bn1 a,sh
//   acc[4..36): bn2 scale      acc[36..68): bn2 shift
//   acc[68..68+4096): bn2 partial sums, idx = 68 + (st*32+c)*64 + slot
//   acc[4164..4164+864): W27 table, idx = c*27 + zc*9 + yc*3 + xc
constexpr int WOFF  = 68 + 64 * 64;      // 4164
constexpr int ACC_N = WOFF + 864;        // 5028

// ---------------- Kernel 1: conv1 (32->1, 3x3x3 SAME) + fuzzy + bn1 stats
// 2z x 4w register tile, branchless clamped loads, depth-1 double-buffer
// (round-2 proven shape: VGPR 116, 88 us).
__global__ __launch_bounds__(256) void k_conv1_fuzzy(
    const float* __restrict__ x, const float* __restrict__ w1,
    const float* __restrict__ b1, const float* __restrict__ mu,
    const float* __restrict__ sg, float* __restrict__ fuzz,
    float* __restrict__ acc)
{
    const int tid = threadIdx.x;
    const int t = blockIdx.x * 256 + tid;        // 131072 threads
    const int wq = t & 15;        const int w0 = wq << 2;
    const int zp = (t >> 4) & 31; const int z0 = zp << 1;
    const int y  = (t >> 9) & 63;
    const int b  = t >> 15;
    const int lane = tid & 63;

    float S1 = 0.f, S2 = 0.f, S3 = 0.f;
#pragma unroll
    for (int n = 0; n < 4; n++) {
        float m = mu[n], s = sg[n];
        float iv = 1.0f / (s * s);
        S1 += iv; S2 += m * iv; S3 += m * m * iv;
    }

    const float b1v = b1[0];
    float a00 = b1v, a01 = b1v, a02 = b1v, a03 = b1v;
    float a10 = b1v, a11 = b1v, a12 = b1v, a13 = b1v;

    const float* xb = x + (size_t)b * Cc * SP;

    // channel-invariant row predicates + CLAMPED offsets (always-valid addrs)
    bool pv[12]; int ofs[12];
#pragma unroll
    for (int rz = 0; rz < 4; rz++) {
        const int zz = z0 - 1 + rz;
        const int zzc = min(max(zz, 0), 63);
        const bool okz = (unsigned)zz < 64u;
#pragma unroll
        for (int dy = 0; dy < 3; dy++) {
            const int yy = y - 1 + dy;
            const int yyc = min(max(yy, 0), 63);
            pv[rz * 3 + dy]  = okz && ((unsigned)yy < 64u);
            ofs[rz * 3 + dy] = (zzc << 12) + (yyc << 6) + w0;
        }
    }

    auto LOADCH = [&](int c, float4 (&M)[12]) {
        const float* xc = xb + (size_t)c * SP;
#pragma unroll
        for (int i = 0; i < 12; i++)
            M[i] = *(const float4*)(xc + ofs[i]);   // unconditional, clustered
    };

    auto COMPUTECH = [&](int c, float4 (&M)[12]) {
        // zero invalid rows (vmcnt wait lands here — loads were issued a full
        // channel-compute earlier)
#pragma unroll
        for (int i = 0; i < 12; i++) {
            M[i].x = pv[i] ? M[i].x : 0.f;
            M[i].y = pv[i] ? M[i].y : 0.f;
            M[i].z = pv[i] ? M[i].z : 0.f;
            M[i].w = pv[i] ? M[i].w : 0.f;
        }
        const float* wc = w1 + c * 27;           // loop-uniform -> s_load
        float Wv[27];
#pragma unroll
        for (int k = 0; k < 27; k++) Wv[k] = wc[k];
#pragma unroll
        for (int rz = 0; rz < 4; rz++) {
#pragma unroll
            for (int dy = 0; dy < 3; dy++) {
                const float4 m = M[rz * 3 + dy];
                const float lv = __shfl(m.w, (lane + 63) & 63, 64);
                const float rv = __shfl(m.x, (lane + 1) & 63, 64);
                const float v0 = (wq > 0)  ? lv : 0.f;
                const float v5 = (wq < 15) ? rv : 0.f;
                const float v1 = m.x, v2 = m.y, v3 = m.z, v4 = m.w;
                if (rz < 3) {
                    const float W0 = Wv[(rz*3+dy)*3], W1 = Wv[(rz*3+dy)*3+1], W2 = Wv[(rz*3+dy)*3+2];
                    a00 = fmaf(v0, W0, fmaf(v1, W1, fmaf(v2, W2, a00)));
                    a01 = fmaf(v1, W0, fmaf(v2, W1, fmaf(v3, W2, a01)));
                    a02 = fmaf(v2, W0, fmaf(v3, W1, fmaf(v4, W2, a02)));
                    a03 = fmaf(v3, W0, fmaf(v4, W1, fmaf(v5, W2, a03)));
                }
                if (rz >= 1) {
                    const float W0 = Wv[((rz-1)*3+dy)*3], W1 = Wv[((rz-1)*3+dy)*3+1], W2 = Wv[((rz-1)*3+dy)*3+2];
                    a10 = fmaf(v0, W0, fmaf(v1, W1, fmaf(v2, W2, a10)));
                    a11 = fmaf(v1, W0, fmaf(v2, W1, fmaf(v3, W2, a11)));
                    a12 = fmaf(v2, W0, fmaf(v3, W1, fmaf(v4, W2, a12)));
                    a13 = fmaf(v3, W0, fmaf(v4, W1, fmaf(v5, W2, a13)));
                }
            }
        }
    };

    float4 Ma[12], Mb[12];
    LOADCH(0, Ma);
    for (int c = 0; c < Cc; c += 2) {
        LOADCH(c + 1, Mb);                 // prefetch while computing c
        COMPUTECH(c, Ma);
        if (c + 2 < Cc) LOADCH(c + 2, Ma); // prefetch while computing c+1
        COMPUTECH(c + 1, Mb);
    }

    // fuzzy + store RAW fuzz into padded layout + bn1 stats
    float fsum = 0.f, fsq = 0.f;
#pragma unroll
    for (int oz = 0; oz < 2; oz++) {
        float xv[4] = { oz ? a10 : a00, oz ? a11 : a01,
                        oz ? a12 : a02, oz ? a13 : a03 };
        float* fp = fuzz + (size_t)b * PSP + (size_t)(z0 + oz + 1) * PZR
                  + (y + 1) * PW + (w0 + 1);
#pragma unroll
        for (int ow = 0; ow < 4; ow++) {
            float x1 = xv[ow];
            float tt = x1 * x1 * S1 - 2.0f * x1 * S2 + S3;
            float fz = __expf(-tt);
            fp[ow] = fz; fsum += fz; fsq += fz * fz;
        }
    }
#pragma unroll
    for (int m = 1; m < 64; m <<= 1) {
        fsum += __shfl_xor(fsum, m, 64);
        fsq  += __shfl_xor(fsq,  m, 64);
    }
    __shared__ float red[8];
    const int wid = tid >> 6;
    if ((tid & 63) == 0) { red[wid * 2] = fsum; red[wid * 2 + 1] = fsq; }
    __syncthreads();
    if (tid == 0) {
        atomicAdd(&acc[0], red[0] + red[2] + red[4] + red[6]);
        atomicAdd(&acc[1], red[1] + red[3] + red[5] + red[7]);
    }
}

// ---------------- Kernel 2: finalize bn1 -> (a, sh); build W27 boundary table.
// W27[c][zc][yc][xc] = sum of w2 taps valid for that boundary class
// (class 0: coord==0 -> d in {1,2}; class 2: coord==63 -> d in {0,1}; else all).
__global__ void k_fin1(const float* __restrict__ g, const float* __restrict__ be,
                       const float* __restrict__ w2, float* __restrict__ acc)
{
    const int tid = threadIdx.x;          // 864 threads
    if (tid == 0) {
        float mean = acc[0] * (1.0f / TS);
        float var  = acc[1] * (1.0f / TS) - mean * mean;
        float a = g[0] * rsqrtf(var + 1e-5f);
        acc[2] = a;
        acc[3] = be[0] - mean * a;
    }
    if (tid < 864) {
        const int c   = tid / 27;
        const int cls = tid - c * 27;
        const int zc  = cls / 9;
        const int r   = cls - zc * 9;
        const int yc  = r / 3;
        const int xc  = r - yc * 3;
        float s = 0.f;
#pragma unroll
        for (int dz = 0; dz < 3; dz++) {
            if ((zc == 0 && dz == 0) || (zc == 2 && dz == 2)) continue;
#pragma unroll
            for (int dy = 0; dy < 3; dy++) {
                if ((yc == 0 && dy == 0) || (yc == 2 && dy == 2)) continue;
#pragma unroll
                for (int dx = 0; dx < 3; dx++) {
                    if ((xc == 0 && dx == 0) || (xc == 2 && dx == 2)) continue;
                    s += w2[c * 27 + (dz * 3 + dy) * 3 + dx];
                }
            }
        }
        acc[WOFF + tid] = s;
    }
}

// ---------------- Kernel 3/5: conv2 on RAW padded fuzz with folded bn1 affine.
//   y = a * (sum w2 * fuzz_raw) + (sh * W27[class] + b2)
// KEY FIX: wid goes through readfirstlane so the per-channel constant stream
// (w2, b2, W27, bn2 scale/shift) is provably wave-uniform -> s_load/SGPR
// operands instead of per-lane vector loads.
template <bool WRITE>
__global__ __launch_bounds__(256) void k_conv2(
    const float* __restrict__ fuzz, const float* __restrict__ w2,
    const float* __restrict__ b2, float* __restrict__ acc,
    float* __restrict__ out)
{
    const int tid = threadIdx.x;
    const int lane = tid & 63;
    const int wid = __builtin_amdgcn_readfirstlane(tid >> 6); // uniform 0..3
    const int bi = blockIdx.x;             // 4096 spatial tiles
    const int w = lane;
    const int y = bi & 63;
    const int z0 = ((bi >> 6) & 15) << 2;
    const int b = bi >> 10;
    const float a = acc[2], sh = acc[3];
    const float* fb = fuzz + (size_t)b * PSP;

    float Fl[6][3], Fm[6][3], Fr[6][3];
#pragma unroll
    for (int rz = 0; rz < 6; rz++) {
#pragma unroll
        for (int dy = 0; dy < 3; dy++) {
            const float* rp = fb + (size_t)(z0 + rz) * PZR + (y + dy) * PW + w;
            Fl[rz][dy] = rp[0];
            Fm[rz][dy] = rp[1];
            Fr[rz][dy] = rp[2];
        }
    }

    // boundary classes: z0+1, z0+2 are always interior (z0 in 0..60 step 4)
    const int yc  = (y == 0) ? 0 : ((y == 63) ? 2 : 1);
    const int zc0 = (z0 == 0) ? 0 : 1;
    const int zc3 = (z0 + 3 == 63) ? 2 : 1;
    const bool lo = (lane == 0), hi = (lane == 63);

    float* ob = out + (size_t)b * Cc * SP + (z0 << 12) + (y << 6) + w;
    const int slot = bi & 63;
    const int c0 = wid * 8;

#pragma unroll
    for (int ci = 0; ci < 8; ci++) {
        const int c = c0 + ci;             // uniform (wid uniform, ci constant)
        const float* wc = w2 + c * 27;     // uniform -> s_load
        float Wv[27];
#pragma unroll
        for (int k = 0; k < 27; k++) Wv[k] = wc[k];
        float o0 = 0.f, o1 = 0.f, o2 = 0.f, o3 = 0.f;
#pragma unroll
        for (int rz = 0; rz < 6; rz++) {
#pragma unroll
            for (int dy = 0; dy < 3; dy++) {
                const float l = Fl[rz][dy], m = Fm[rz][dy], r = Fr[rz][dy];
#pragma unroll
                for (int oz = 0; oz < 4; oz++) {
                    const int dz = rz - oz;
                    if (dz < 0 || dz > 2) continue;
                    const float W0 = Wv[(dz*3+dy)*3], W1 = Wv[(dz*3+dy)*3+1], W2 = Wv[(dz*3+dy)*3+2];
                    if      (oz == 0) o0 = fmaf(l, W0, fmaf(m, W1, fmaf(r, W2, o0)));
                    else if (oz == 1) o1 = fmaf(l, W0, fmaf(m, W1, fmaf(r, W2, o1)));
                    else if (oz == 2) o2 = fmaf(l, W0, fmaf(m, W1, fmaf(r, W2, o2)));
                    else              o3 = fmaf(l, W0, fmaf(m, W1, fmaf(r, W2, o3)));
                }
            }
        }
        // per-oz bn1-fold offsets: off = b2 + sh * W27[c][zc][yc][xc(lane)]
        const float bb = b2[c];                           // uniform -> s_load
        const float* tb = acc + WOFF + c * 27 + yc * 3;   // + zc*9 + xc
        const float* t0 = tb + zc0 * 9;
        const float* t1 = tb + 9;                          // zc == 1
        const float* t3 = tb + zc3 * 9;
        const float w0s = lo ? t0[0] : (hi ? t0[2] : t0[1]);
        const float w1s = lo ? t1[0] : (hi ? t1[2] : t1[1]);
        const float w3s = lo ? t3[0] : (hi ? t3[2] : t3[1]);
        const float off0 = fmaf(sh, w0s, bb);
        const float off1 = fmaf(sh, w1s, bb);   // oz=1 and oz=2 share class
        const float off3 = fmaf(sh, w3s, bb);
        const float v0 = fmaf(o0, a, off0);
        const float v1 = fmaf(o1, a, off1);
        const float v2 = fmaf(o2, a, off1);
        const float v3 = fmaf(o3, a, off3);

        if (WRITE) {
            const float sc = acc[4 + c], s2 = acc[36 + c];  // uniform -> s_load
            ob[(size_t)c * SP]         = fmaf(v0, sc, s2);
            ob[(size_t)c * SP + 4096]  = fmaf(v1, sc, s2);
            ob[(size_t)c * SP + 8192]  = fmaf(v2, sc, s2);
            ob[(size_t)c * SP + 12288] = fmaf(v3, sc, s2);
        } else {
            float ps = (v0 + v1) + (v2 + v3);
            float pq = fmaf(v0, v0, fmaf(v1, v1, fmaf(v2, v2, v3 * v3)));
#pragma unroll
            for (int mm = 1; mm < 64; mm <<= 1) {
                ps += __shfl_xor(ps, mm, 64);
                pq += __shfl_xor(pq, mm, 64);
            }
            if (lane == 0) {
                atomicAdd(&acc[68 + c * 64 + slot], ps);
                atomicAdd(&acc[68 + (32 + c) * 64 + slot], pq);
            }
        }
    }
}

// ---------------- Kernel 4: finalize bn2 (parallel: 1024 threads, shfl-reduce)
__global__ void k_fin2(const float* __restrict__ g, const float* __restrict__ be,
                       float* __restrict__ acc)
{
    const int tid = threadIdx.x;          // 1024 threads
    const int c = tid >> 5, j = tid & 31;
    float s = acc[68 + c * 64 + j]        + acc[68 + c * 64 + 32 + j];
    float q = acc[68 + (32 + c) * 64 + j] + acc[68 + (32 + c) * 64 + 32 + j];
#pragma unroll
    for (int m = 1; m < 32; m <<= 1) {
        s += __shfl_xor(s, m, 32);
        q += __shfl_xor(q, m, 32);
    }
    if (j == 0) {
        float mean = s * (1.0f / TS);
        float var  = q * (1.0f / TS) - mean * mean;
        float sc = g[c] * rsqrtf(var + 1e-5f);
        acc[4 + c]  = sc;
        acc[36 + c] = be[c] - mean * sc;
    }
}

extern "C" void kernel_launch(void* const* d_in, const int* in_sizes, int n_in,
                              void* d_out, int out_size, void* d_ws, size_t ws_size,
                              hipStream_t stream)
{
    const float* x   = (const float*)d_in[0];
    const float* w1  = (const float*)d_in[1];
    const float* b1  = (const float*)d_in[2];
    const float* w2  = (const float*)d_in[3];
    const float* b2  = (const float*)d_in[4];
    const float* mu  = (const float*)d_in[5];
    const float* sg  = (const float*)d_in[6];
    const float* g1  = (const float*)d_in[7];
    const float* be1 = (const float*)d_in[8];
    const float* g2  = (const float*)d_in[9];
    const float* be2 = (const float*)d_in[10];

    float* out  = (float*)d_out;
    float* fuzz = (float*)d_ws;
    float* acc  = fuzz + PTOT;

    // zero padded fuzz (pad ring must be 0 each launch) + acc area in one shot
    hipMemsetAsync(fuzz, 0, (size_t)(PTOT + ACC_N) * sizeof(float), stream);
    k_conv1_fuzzy<<<512, 256, 0, stream>>>(x, w1, b1, mu, sg, fuzz, acc);
    k_fin1<<<1, 864, 0, stream>>>(g1, be1, w2, acc);
    k_conv2<false><<<4096, 256, 0, stream>>>(fuzz, w2, b2, acc, out);
    k_fin2<<<1, 1024, 0, stream>>>(g2, be2, acc);
    k_conv2<true><<<4096, 256, 0, stream>>>(fuzz, w2, b2, acc, out);
}